// Round 2
// baseline (235.797 us; speedup 1.0000x reference)
//
#include <hip/hip_runtime.h>

constexpr int VOL = 32 * 32 * 32 * 32;   // 1048576 sites
constexpr float KAPPA = 0.1f;            // kappa/u0

// ---------------------------------------------------------------------------
// Half-spinor projection: h = rows01 of (I - S*gamma_mu) psi,  S=+1 fwd, -1 bwd
//   mu=0: h0 = p0 - S*i*p3 ; h1 = p1 - S*i*p2
//   mu=1: h0 = p0 + S*p3   ; h1 = p1 - S*p2
//   mu=2: h0 = p0 - S*i*p2 ; h1 = p1 + S*i*p3
//   mu=3: h0 = p0 - S*p2   ; h1 = p1 - S*p3
// ---------------------------------------------------------------------------
template <int MU, int S>
__device__ __forceinline__ void project(const float pr[4][3], const float pi[4][3],
                                        float hr[2][3], float hi[2][3]) {
    const float s = (float)S;
#pragma unroll
    for (int c = 0; c < 3; ++c) {
        if (MU == 0) {
            hr[0][c] = pr[0][c] + s * pi[3][c];
            hi[0][c] = pi[0][c] - s * pr[3][c];
            hr[1][c] = pr[1][c] + s * pi[2][c];
            hi[1][c] = pi[1][c] - s * pr[2][c];
        } else if (MU == 1) {
            hr[0][c] = pr[0][c] + s * pr[3][c];
            hi[0][c] = pi[0][c] + s * pi[3][c];
            hr[1][c] = pr[1][c] - s * pr[2][c];
            hi[1][c] = pi[1][c] - s * pi[2][c];
        } else if (MU == 2) {
            hr[0][c] = pr[0][c] + s * pi[2][c];
            hi[0][c] = pi[0][c] - s * pr[2][c];
            hr[1][c] = pr[1][c] - s * pi[3][c];
            hi[1][c] = pi[1][c] + s * pr[3][c];
        } else {
            hr[0][c] = pr[0][c] - s * pr[2][c];
            hi[0][c] = pi[0][c] - s * pi[2][c];
            hr[1][c] = pr[1][c] - s * pr[3][c];
            hi[1][c] = pi[1][c] - s * pi[3][c];
        }
    }
}

// chi[a] = sum_b W[a][b] * h[b], W = U (DAG=false) or U^dagger (DAG=true)
template <bool DAG>
__device__ __forceinline__ void mul_u(const float* __restrict__ Ure,
                                      const float* __restrict__ Uim,
                                      int mu, int site,
                                      const float hr[2][3], const float hi[2][3],
                                      float xr[2][3], float xi[2][3]) {
    float ur[3][3], ui[3][3];
#pragma unroll
    for (int a = 0; a < 3; ++a)
#pragma unroll
        for (int b = 0; b < 3; ++b) {
            int idx = ((a * 3 + b) * 4 + mu) * VOL + site;
            ur[a][b] = Ure[idx];
            ui[a][b] = Uim[idx];
        }
#pragma unroll
    for (int h = 0; h < 2; ++h)
#pragma unroll
        for (int a = 0; a < 3; ++a) {
            float ar = 0.f, ai = 0.f;
#pragma unroll
            for (int b = 0; b < 3; ++b) {
                float wr = DAG ? ur[b][a] : ur[a][b];
                float wi = DAG ? -ui[b][a] : ui[a][b];
                ar += wr * hr[h][b] - wi * hi[h][b];
                ai += wr * hi[h][b] + wi * hr[h][b];
            }
            xr[h][a] = ar;
            xi[h][a] = ai;
        }
}

// dest_re -= kappa * Re(reconstruct(chi)).  Rows 0,1 get chi directly; rows 2,3:
//   mu=0: r2 = S*i*chi1 ; r3 = S*i*chi0     (Re = -S*Im(chi))
//   mu=1: r2 = -S*chi1  ; r3 = S*chi0
//   mu=2: r2 = S*i*chi0 ; r3 = -S*i*chi1
//   mu=3: r2 = -S*chi0  ; r3 = -S*chi1
// Only the REAL part of dest is needed (harness keeps Re only).
template <int MU, int S>
__device__ __forceinline__ void accum(float dr[4][3],
                                      const float xr[2][3], const float xi[2][3]) {
    const float k = KAPPA;
    const float ks = KAPPA * (float)S;
#pragma unroll
    for (int c = 0; c < 3; ++c) {
        dr[0][c] -= k * xr[0][c];
        dr[1][c] -= k * xr[1][c];
        if (MU == 0) {
            dr[2][c] += ks * xi[1][c];
            dr[3][c] += ks * xi[0][c];
        } else if (MU == 1) {
            dr[2][c] += ks * xr[1][c];
            dr[3][c] -= ks * xr[0][c];
        } else if (MU == 2) {
            dr[2][c] += ks * xi[0][c];
            dr[3][c] -= ks * xi[1][c];
        } else {
            dr[2][c] += ks * xr[0][c];
            dr[3][c] += ks * xr[1][c];
        }
    }
}

__device__ __forceinline__ void load_spinor(const float* __restrict__ re,
                                            const float* __restrict__ im,
                                            int site, float pr[4][3], float pi[4][3]) {
#pragma unroll
    for (int s = 0; s < 4; ++s)
#pragma unroll
        for (int c = 0; c < 3; ++c) {
            int idx = (s * 3 + c) * VOL + site;
            pr[s][c] = re[idx];
            pi[s][c] = im[idx];
        }
}

template <int MU, bool FWD>
__device__ __forceinline__ void hop(const float* __restrict__ sre,
                                    const float* __restrict__ sim,
                                    const float* __restrict__ Ure,
                                    const float* __restrict__ Uim,
                                    int site, int nsite,
                                    float dr[4][3]) {
    float pr[4][3], pi[4][3], hr[2][3], hi[2][3], xr[2][3], xi[2][3];
    load_spinor(sre, sim, nsite, pr, pi);
    if (FWD) {
        project<MU, 1>(pr, pi, hr, hi);
        mul_u<false>(Ure, Uim, MU, site, hr, hi, xr, xi);   // U_mu(x)
        accum<MU, 1>(dr, xr, xi);
    } else {
        project<MU, -1>(pr, pi, hr, hi);
        mul_u<true>(Ure, Uim, MU, nsite, hr, hi, xr, xi);   // U_mu(x-mu)^dag
        accum<MU, -1>(dr, xr, xi);
    }
}

__global__ __launch_bounds__(256)
void wilson_kernel(const float* __restrict__ src_re, const float* __restrict__ src_im,
                   const float* __restrict__ U_re, const float* __restrict__ U_im,
                   float* __restrict__ out) {
    int site = blockIdx.x * blockDim.x + threadIdx.x;
    if (site >= VOL) return;

    int x = site & 31;
    int y = (site >> 5) & 31;
    int z = (site >> 10) & 31;
    int t = (site >> 15) & 31;

    // dest_re = src_re (central term); imag of dest is never stored
    float dr[4][3];
#pragma unroll
    for (int s = 0; s < 4; ++s)
#pragma unroll
        for (int c = 0; c < 3; ++c)
            dr[s][c] = src_re[(s * 3 + c) * VOL + site];

    int sxp = (site & ~31) | ((x + 1) & 31);
    int sxm = (site & ~31) | ((x + 31) & 31);
    int syp = (site & ~(31 << 5)) | (((y + 1) & 31) << 5);
    int sym = (site & ~(31 << 5)) | (((y + 31) & 31) << 5);
    int szp = (site & ~(31 << 10)) | (((z + 1) & 31) << 10);
    int szm = (site & ~(31 << 10)) | (((z + 31) & 31) << 10);
    int stp = (site & ~(31 << 15)) | (((t + 1) & 31) << 15);
    int stm = (site & ~(31 << 15)) | (((t + 31) & 31) << 15);

    hop<0, true >(src_re, src_im, U_re, U_im, site, sxp, dr);
    hop<0, false>(src_re, src_im, U_re, U_im, site, sxm, dr);
    hop<1, true >(src_re, src_im, U_re, U_im, site, syp, dr);
    hop<1, false>(src_re, src_im, U_re, U_im, site, sym, dr);
    hop<2, true >(src_re, src_im, U_re, U_im, site, szp, dr);
    hop<2, false>(src_re, src_im, U_re, U_im, site, szm, dr);
    hop<3, true >(src_re, src_im, U_re, U_im, site, stp, dr);
    hop<3, false>(src_re, src_im, U_re, U_im, site, stm, dr);

#pragma unroll
    for (int s = 0; s < 4; ++s)
#pragma unroll
        for (int c = 0; c < 3; ++c)
            out[(s * 3 + c) * VOL + site] = dr[s][c];
}

extern "C" void kernel_launch(void* const* d_in, const int* in_sizes, int n_in,
                              void* d_out, int out_size, void* d_ws, size_t ws_size,
                              hipStream_t stream) {
    const float* src_re = (const float*)d_in[0];
    const float* src_im = (const float*)d_in[1];
    const float* U_re   = (const float*)d_in[2];
    const float* U_im   = (const float*)d_in[3];
    float* out = (float*)d_out;

    dim3 block(256);
    dim3 grid(VOL / 256);
    wilson_kernel<<<grid, block, 0, stream>>>(src_re, src_im, U_re, U_im, out);
}

// Round 3
// 235.431 us; speedup vs baseline: 1.0016x; 1.0016x over previous
//
#include <hip/hip_runtime.h>

constexpr int VOL = 32 * 32 * 32 * 32;   // 1048576 sites
constexpr float KAPPA = 0.1f;            // kappa/u0

// 16B-aligned 4-float vector (4 consecutive x-sites per thread).
struct alignas(16) F4 { float x, y, z, w; };

__device__ __forceinline__ F4 operator+(F4 a, F4 b) { return F4{a.x + b.x, a.y + b.y, a.z + b.z, a.w + b.w}; }
__device__ __forceinline__ F4 operator-(F4 a, F4 b) { return F4{a.x - b.x, a.y - b.y, a.z - b.z, a.w - b.w}; }
__device__ __forceinline__ F4 operator*(F4 a, F4 b) { return F4{a.x * b.x, a.y * b.y, a.z * b.z, a.w * b.w}; }
__device__ __forceinline__ F4 operator*(float s, F4 a) { return F4{s * a.x, s * a.y, s * a.z, s * a.w}; }

__device__ __forceinline__ F4 ld4(const float* __restrict__ p, int idx) {
    return *reinterpret_cast<const F4*>(p + idx);
}

// --- spinor loaders: produce float4 (re,im) for spin s, color c ---
struct Direct {            // neighbor in y/z/t: same x-group, different site
    const float* re; const float* im; int site;
    __device__ __forceinline__ void load(int s, int c, F4& r, F4& i) const {
        int idx = (s * 3 + c) * VOL + site;
        r = ld4(re, idx); i = ld4(im, idx);
    }
};
struct ShiftR {            // x+1 window (x+1..x+4): {c.y,c.z,c.w,r.x}
    const float* re; const float* im; int cs, rs;
    __device__ __forceinline__ void load(int s, int c, F4& r, F4& i) const {
        int o = (s * 3 + c) * VOL;
        F4 cr = ld4(re, o + cs), rr = ld4(re, o + rs);
        F4 ci = ld4(im, o + cs), ri = ld4(im, o + rs);
        r = F4{cr.y, cr.z, cr.w, rr.x};
        i = F4{ci.y, ci.z, ci.w, ri.x};
    }
};
struct ShiftL {            // x-1 window (x-1..x+2): {l.w,c.x,c.y,c.z}
    const float* re; const float* im; int ls, cs;
    __device__ __forceinline__ void load(int s, int c, F4& r, F4& i) const {
        int o = (s * 3 + c) * VOL;
        F4 lr = ld4(re, o + ls), cr = ld4(re, o + cs);
        F4 li = ld4(im, o + ls), ci = ld4(im, o + cs);
        r = F4{lr.w, cr.x, cr.y, cr.z};
        i = F4{li.w, ci.x, ci.y, ci.z};
    }
};

// --- U loaders: produce float4 (re,im) of U[a][b] at the link site ---
struct UDirect {
    const float* re; const float* im; int mu, site;
    __device__ __forceinline__ void load(int a, int b, F4& r, F4& i) const {
        int idx = ((a * 3 + b) * 4 + mu) * VOL + site;
        r = ld4(re, idx); i = ld4(im, idx);
    }
};
struct UShiftL {           // U_x at x-1..x+2 window
    const float* re; const float* im; int mu, ls, cs;
    __device__ __forceinline__ void load(int a, int b, F4& r, F4& i) const {
        int o = ((a * 3 + b) * 4 + mu) * VOL;
        F4 lr = ld4(re, o + ls), cr = ld4(re, o + cs);
        F4 li = ld4(im, o + ls), ci = ld4(im, o + cs);
        r = F4{lr.w, cr.x, cr.y, cr.z};
        i = F4{li.w, ci.x, ci.y, ci.z};
    }
};

// One hopping term: project (I - S*gamma_mu), multiply by U (S=+1) or U^dag
// (S=-1), reconstruct, accumulate REAL part into dr (imag never stored).
// Projection (rows 0,1 of (I - S*gamma_mu)psi), basis verified in R2:
//   mu=0: h0 = p0 + S*i_conj... (see formulas inline)
// Reconstruction rows 2,3 need Im(chi) only for mu=0,2; Re(chi) only for mu=1,3.
template <int MU, int S, class SL, class UL>
__device__ __forceinline__ void hop(const SL& sl, const UL& ul, F4 dr[4][3]) {
    constexpr bool DAG = (S < 0);
    constexpr bool NEEDI = (MU == 0 || MU == 2);
    const float s = (float)S;

    F4 hr[2][3], hi[2][3];
#pragma unroll
    for (int c = 0; c < 3; ++c) {
        F4 p0r, p0i, p1r, p1i, p2r, p2i, p3r, p3i;
        sl.load(0, c, p0r, p0i);
        sl.load(1, c, p1r, p1i);
        sl.load(2, c, p2r, p2i);
        sl.load(3, c, p3r, p3i);
        if (MU == 0) {
            hr[0][c] = p0r + s * p3i;  hi[0][c] = p0i - s * p3r;
            hr[1][c] = p1r + s * p2i;  hi[1][c] = p1i - s * p2r;
        } else if (MU == 1) {
            hr[0][c] = p0r + s * p3r;  hi[0][c] = p0i + s * p3i;
            hr[1][c] = p1r - s * p2r;  hi[1][c] = p1i - s * p2i;
        } else if (MU == 2) {
            hr[0][c] = p0r + s * p2i;  hi[0][c] = p0i - s * p2r;
            hr[1][c] = p1r - s * p3i;  hi[1][c] = p1i + s * p3r;
        } else {
            hr[0][c] = p0r - s * p2r;  hi[0][c] = p0i - s * p2i;
            hr[1][c] = p1r - s * p3r;  hi[1][c] = p1i - s * p3i;
        }
    }

    const float k = KAPPA, ks = KAPPA * s;
#pragma unroll
    for (int a = 0; a < 3; ++a) {
        // W[a][b] = DAG ? conj(U[b][a]) : U[a][b]
        F4 wr[3], wi[3];
#pragma unroll
        for (int b = 0; b < 3; ++b) {
            F4 r, i;
            if (DAG) { ul.load(b, a, r, i); wi[b] = F4{-i.x, -i.y, -i.z, -i.w}; }
            else     { ul.load(a, b, r, i); wi[b] = i; }
            wr[b] = r;
        }
        F4 ar0{0,0,0,0}, ar1{0,0,0,0}, ai0{0,0,0,0}, ai1{0,0,0,0};
#pragma unroll
        for (int b = 0; b < 3; ++b) {
            ar0 = ar0 + wr[b] * hr[0][b] - wi[b] * hi[0][b];
            ar1 = ar1 + wr[b] * hr[1][b] - wi[b] * hi[1][b];
            if (NEEDI) {
                ai0 = ai0 + wr[b] * hi[0][b] + wi[b] * hr[0][b];
                ai1 = ai1 + wr[b] * hi[1][b] + wi[b] * hr[1][b];
            }
        }
        dr[0][a] = dr[0][a] - k * ar0;
        dr[1][a] = dr[1][a] - k * ar1;
        if (MU == 0)      { dr[2][a] = dr[2][a] + ks * ai1; dr[3][a] = dr[3][a] + ks * ai0; }
        else if (MU == 1) { dr[2][a] = dr[2][a] + ks * ar1; dr[3][a] = dr[3][a] - ks * ar0; }
        else if (MU == 2) { dr[2][a] = dr[2][a] + ks * ai0; dr[3][a] = dr[3][a] - ks * ai1; }
        else              { dr[2][a] = dr[2][a] + ks * ar0; dr[3][a] = dr[3][a] + ks * ar1; }
    }
}

__global__ __launch_bounds__(256)
void wilson_kernel(const float* __restrict__ src_re, const float* __restrict__ src_im,
                   const float* __restrict__ U_re, const float* __restrict__ U_im,
                   float* __restrict__ out) {
    int tid = blockIdx.x * blockDim.x + threadIdx.x;
    int site = tid << 2;                 // 4 consecutive x-sites per thread

    int x4 = site & 31;                  // x of group start (multiple of 4)
    int lbase = site & ~31;
    int sR = lbase | ((x4 + 4) & 31);    // right x-group (wrapped)
    int sL = lbase | ((x4 + 28) & 31);   // left  x-group (wrapped)

    int y = (site >> 5) & 31;
    int z = (site >> 10) & 31;
    int t = (site >> 15) & 31;
    int syp = (site & ~(31 << 5))  | (((y + 1)  & 31) << 5);
    int sym = (site & ~(31 << 5))  | (((y + 31) & 31) << 5);
    int szp = (site & ~(31 << 10)) | (((z + 1)  & 31) << 10);
    int szm = (site & ~(31 << 10)) | (((z + 31) & 31) << 10);
    int stp = (site & ~(31 << 15)) | (((t + 1)  & 31) << 15);
    int stm = (site & ~(31 << 15)) | (((t + 31) & 31) << 15);

    // central term: dest_re = src_re
    F4 dr[4][3];
#pragma unroll
    for (int s = 0; s < 4; ++s)
#pragma unroll
        for (int c = 0; c < 3; ++c)
            dr[s][c] = ld4(src_re, (s * 3 + c) * VOL + site);

    hop<0,  1>(ShiftR{src_re, src_im, site, sR},   UDirect{U_re, U_im, 0, site}, dr);
    hop<0, -1>(ShiftL{src_re, src_im, sL, site},   UShiftL{U_re, U_im, 0, sL, site}, dr);
    hop<1,  1>(Direct{src_re, src_im, syp},        UDirect{U_re, U_im, 1, site}, dr);
    hop<1, -1>(Direct{src_re, src_im, sym},        UDirect{U_re, U_im, 1, sym}, dr);
    hop<2,  1>(Direct{src_re, src_im, szp},        UDirect{U_re, U_im, 2, site}, dr);
    hop<2, -1>(Direct{src_re, src_im, szm},        UDirect{U_re, U_im, 2, szm}, dr);
    hop<3,  1>(Direct{src_re, src_im, stp},        UDirect{U_re, U_im, 3, site}, dr);
    hop<3, -1>(Direct{src_re, src_im, stm},        UDirect{U_re, U_im, 3, stm}, dr);

#pragma unroll
    for (int s = 0; s < 4; ++s)
#pragma unroll
        for (int c = 0; c < 3; ++c)
            *reinterpret_cast<F4*>(out + (s * 3 + c) * VOL + site) = dr[s][c];
}

extern "C" void kernel_launch(void* const* d_in, const int* in_sizes, int n_in,
                              void* d_out, int out_size, void* d_ws, size_t ws_size,
                              hipStream_t stream) {
    const float* src_re = (const float*)d_in[0];
    const float* src_im = (const float*)d_in[1];
    const float* U_re   = (const float*)d_in[2];
    const float* U_im   = (const float*)d_in[3];
    float* out = (float*)d_out;

    dim3 block(256);
    dim3 grid(VOL / 4 / 256);            // 4 sites per thread
    wilson_kernel<<<grid, block, 0, stream>>>(src_re, src_im, U_re, U_im, out);
}